// Round 1
// baseline (646.889 us; speedup 1.0000x reference)
//
#include <hip/hip_runtime.h>
#include <hip/hip_bf16.h>
#include <stdint.h>

#define L_SEQ 8192
#define S_SEQ 512
#define DIM   2048
#define CTX   4096
#define NH    16
#define HD    128

typedef __bf16 bf16_t;
typedef bf16_t bf16x8 __attribute__((ext_vector_type(8)));
typedef float  f32x4_t __attribute__((ext_vector_type(4)));

__device__ __forceinline__ ushort f2b(float f) {
  union { float f; uint32_t u; } v; v.f = f;
  uint32_t u = v.u;
  uint32_t r = (u + 0x7fffu + ((u >> 16) & 1u)) >> 16;
  return (ushort)r;
}
__device__ __forceinline__ uint32_t pk2(float a, float b) {
  return (uint32_t)f2b(a) | ((uint32_t)f2b(b) << 16);
}

// ---------------- transpose + cast fp32 [K][N] -> bf16 [N][K] ----------------
__global__ __launch_bounds__(256) void k_tcast(const float* __restrict__ src,
                                               ushort* __restrict__ dst, int K, int N) {
  __shared__ float t[32][33];
  int tx = threadIdx.x, ty = threadIdx.y;
  int n0 = blockIdx.x * 32, k0 = blockIdx.y * 32;
#pragma unroll
  for (int i = 0; i < 4; i++)
    t[ty + 8 * i][tx] = src[(size_t)(k0 + ty + 8 * i) * N + n0 + tx];
  __syncthreads();
#pragma unroll
  for (int i = 0; i < 4; i++)
    dst[(size_t)(n0 + ty + 8 * i) * K + k0 + tx] = f2b(t[tx][ty + 8 * i]);
}

// ---------------- RMSNorm row kernel: fp32 [rows][2048] -> bf16, fused extra scale ----
__global__ __launch_bounds__(256) void k_rmsnorm(const float* __restrict__ in,
                                                 ushort* __restrict__ out,
                                                 const float* __restrict__ g, float scale) {
  const int row = blockIdx.x, tid = threadIdx.x;
  const float* p = in + (size_t)row * DIM + tid * 8;
  float4 v0 = *(const float4*)p;
  float4 v1 = *(const float4*)(p + 4);
  float s = v0.x * v0.x + v0.y * v0.y + v0.z * v0.z + v0.w * v0.w +
            v1.x * v1.x + v1.y * v1.y + v1.z * v1.z + v1.w * v1.w;
#pragma unroll
  for (int off = 32; off; off >>= 1) s += __shfl_down(s, off);
  __shared__ float wsum[4];
  __shared__ float rtot;
  if ((tid & 63) == 0) wsum[tid >> 6] = s;
  __syncthreads();
  if (tid == 0)
    rtot = rsqrtf((wsum[0] + wsum[1] + wsum[2] + wsum[3]) * (1.0f / DIM) + 1e-6f);
  __syncthreads();
  const float rms = rtot * scale;
  const float* gp = g + tid * 8;
  float4 g0 = *(const float4*)gp, g1 = *(const float4*)(gp + 4);
  ushort r[8];
  r[0] = f2b(v0.x * rms * g0.x); r[1] = f2b(v0.y * rms * g0.y);
  r[2] = f2b(v0.z * rms * g0.z); r[3] = f2b(v0.w * rms * g0.w);
  r[4] = f2b(v1.x * rms * g1.x); r[5] = f2b(v1.y * rms * g1.y);
  r[6] = f2b(v1.z * rms * g1.z); r[7] = f2b(v1.w * rms * g1.w);
  *(uint4*)(out + (size_t)row * DIM + tid * 8) = *(uint4*)r;
}

// ---------------- GEMM: C[M,N] = A[M,K] @ Bt[N,K]^T + bias ----------------
// OUT_MODE 0: fp32 out [M,N].  OUT_MODE 2: bf16 out transposed [N,M] (for V^T).
// ALOAD 0: A is bf16.  ALOAD 1: A is fp32 (converted during staging).
template <int OUT_MODE, int ALOAD>
__global__ __launch_bounds__(256) void k_gemm_bt(const void* __restrict__ Avp,
                                                 const ushort* __restrict__ Bt,
                                                 const float* __restrict__ bias,
                                                 void* __restrict__ outp,
                                                 int M, int N, int K) {
  __shared__ __align__(16) ushort As[128 * 40];  // rows stride 40 ushorts (odd 16B units)
  __shared__ __align__(16) ushort Bs[128 * 40];
  const int tid = threadIdx.x;
  const int l = tid & 63, wid = tid >> 6;
  const int wr = wid >> 1, wc = wid & 1;
  const int lr = l & 15, lq = l >> 4;
  const int m0 = blockIdx.y * 128, n0 = blockIdx.x * 128;

  f32x4_t acc[4][4];
#pragma unroll
  for (int i = 0; i < 4; i++)
#pragma unroll
    for (int j = 0; j < 4; j++) acc[i][j] = f32x4_t{0.f, 0.f, 0.f, 0.f};

  const int NT = K >> 5;
  const int c0 = tid, c1 = tid + 256;
  const int ar0 = c0 >> 2, au0 = c0 & 3;
  const int ar1 = c1 >> 2, au1 = c1 & 3;

  auto loadA = [&](int kt, int i) -> uint4 {
    const int row = i ? ar1 : ar0, u = i ? au1 : au0;
    const size_t off = (size_t)(m0 + row) * K + kt * 32 + u * 8;
    if constexpr (ALOAD == 1) {
      const float* Af = (const float*)Avp;
      float4 f0 = *(const float4*)(Af + off);
      float4 f1 = *(const float4*)(Af + off + 4);
      uint4 r;
      r.x = pk2(f0.x, f0.y); r.y = pk2(f0.z, f0.w);
      r.z = pk2(f1.x, f1.y); r.w = pk2(f1.z, f1.w);
      return r;
    } else {
      return *(const uint4*)((const ushort*)Avp + off);
    }
  };
  auto loadB = [&](int kt, int i) -> uint4 {
    const int row = i ? ar1 : ar0, u = i ? au1 : au0;
    return *(const uint4*)(Bt + (size_t)(n0 + row) * K + kt * 32 + u * 8);
  };

  uint4 ra[2], rb[2];
  ra[0] = loadA(0, 0); ra[1] = loadA(0, 1);
  rb[0] = loadB(0, 0); rb[1] = loadB(0, 1);

  for (int kt = 0; kt < NT; kt++) {
    __syncthreads();
    *(uint4*)(&As[ar0 * 40 + au0 * 8]) = ra[0];
    *(uint4*)(&As[ar1 * 40 + au1 * 8]) = ra[1];
    *(uint4*)(&Bs[ar0 * 40 + au0 * 8]) = rb[0];
    *(uint4*)(&Bs[ar1 * 40 + au1 * 8]) = rb[1];
    if (kt + 1 < NT) {  // prefetch next tile; overlaps with compute below
      ra[0] = loadA(kt + 1, 0); ra[1] = loadA(kt + 1, 1);
      rb[0] = loadB(kt + 1, 0); rb[1] = loadB(kt + 1, 1);
    }
    __syncthreads();
    bf16x8 af[4], bfr[4];
#pragma unroll
    for (int mi = 0; mi < 4; mi++)
      af[mi] = *(const bf16x8*)(&As[(wr * 64 + mi * 16 + lr) * 40 + lq * 8]);
#pragma unroll
    for (int ni = 0; ni < 4; ni++)
      bfr[ni] = *(const bf16x8*)(&Bs[(wc * 64 + ni * 16 + lr) * 40 + lq * 8]);
#pragma unroll
    for (int mi = 0; mi < 4; mi++)
#pragma unroll
      for (int ni = 0; ni < 4; ni++)
        acc[mi][ni] = __builtin_amdgcn_mfma_f32_16x16x32_bf16(af[mi], bfr[ni], acc[mi][ni], 0, 0, 0);
  }

#pragma unroll
  for (int mi = 0; mi < 4; mi++) {
#pragma unroll
    for (int ni = 0; ni < 4; ni++) {
      const int col = n0 + wc * 64 + ni * 16 + lr;
      const float bv = bias[col];
#pragma unroll
      for (int r = 0; r < 4; r++) {
        const int row = m0 + wr * 64 + mi * 16 + lq * 4 + r;
        const float v = acc[mi][ni][r] + bv;
        if constexpr (OUT_MODE == 0)
          ((float*)outp)[(size_t)row * N + col] = v;
        else
          ((ushort*)outp)[(size_t)col * M + row] = f2b(v);  // transposed bf16 (V^T)
      }
    }
  }
}

// ---------------- Flash attention: 4 waves x 16 q-rows, KV block 64 ----------------
__global__ __launch_bounds__(256) void k_attn(const ushort* __restrict__ Qb,
                                              const ushort* __restrict__ Kb,
                                              const ushort* __restrict__ Vt,
                                              ushort* __restrict__ Ob) {
  __shared__ __align__(16) ushort Ks[64 * 136];   // [kv 64][d 128], stride 136 (odd units)
  __shared__ __align__(16) ushort Vs[128 * 72];   // [d 128][s 64], stride 72
  __shared__ __align__(16) ushort Ps[4][16 * 72]; // per-wave P tile [16][64], stride 72
  const int tid = threadIdx.x;
  const int l = tid & 63, wid = tid >> 6;
  const int lr = l & 15, lq = l >> 4;
  const int h = blockIdx.y;
  const int q0 = blockIdx.x * 64 + wid * 16;

  bf16x8 aq[4];
  {
    const ushort* qp = Qb + (size_t)(q0 + lr) * DIM + h * HD;
#pragma unroll
    for (int kk = 0; kk < 4; kk++) aq[kk] = *(const bf16x8*)(qp + kk * 32 + lq * 8);
  }
  f32x4_t o[8];
#pragma unroll
  for (int i = 0; i < 8; i++) o[i] = f32x4_t{0.f, 0.f, 0.f, 0.f};
  float mrow[4] = {-1e30f, -1e30f, -1e30f, -1e30f};
  float lrow[4] = {0.f, 0.f, 0.f, 0.f};

  auto loadK = [&](int kvb, int i) -> uint4 {
    const int c = i * 256 + tid, row = c >> 4, u = c & 15;
    return *(const uint4*)(Kb + (size_t)(kvb * 64 + row) * DIM + h * HD + u * 8);
  };
  auto loadV = [&](int kvb, int i) -> uint4 {
    const int c = i * 256 + tid, d = c >> 3, u = c & 7;
    return *(const uint4*)(Vt + (size_t)(h * HD + d) * S_SEQ + kvb * 64 + u * 8);
  };
  uint4 rk[4], rv[4];
#pragma unroll
  for (int i = 0; i < 4; i++) { rk[i] = loadK(0, i); rv[i] = loadV(0, i); }

  for (int kvb = 0; kvb < S_SEQ / 64; kvb++) {
    __syncthreads();
#pragma unroll
    for (int i = 0; i < 4; i++) {
      const int c = i * 256 + tid;
      *(uint4*)(&Ks[(c >> 4) * 136 + (c & 15) * 8]) = rk[i];
      *(uint4*)(&Vs[(c >> 3) * 72 + (c & 7) * 8]) = rv[i];
    }
    if (kvb + 1 < S_SEQ / 64) {
#pragma unroll
      for (int i = 0; i < 4; i++) { rk[i] = loadK(kvb + 1, i); rv[i] = loadV(kvb + 1, i); }
    }
    __syncthreads();

    // scores: S = Q @ K^T  (scale pre-folded into Q)
    f32x4_t s[4];
#pragma unroll
    for (int t = 0; t < 4; t++) {
      s[t] = f32x4_t{0.f, 0.f, 0.f, 0.f};
#pragma unroll
      for (int kk = 0; kk < 4; kk++) {
        bf16x8 bk = *(const bf16x8*)(&Ks[(t * 16 + lr) * 136 + kk * 32 + lq * 8]);
        s[t] = __builtin_amdgcn_mfma_f32_16x16x32_bf16(aq[kk], bk, s[t], 0, 0, 0);
      }
    }
    // online softmax (row r of lane = q-row lq*4+r; 16 lanes share a row)
    float corr[4];
#pragma unroll
    for (int r = 0; r < 4; r++) {
      float rm = fmaxf(fmaxf(s[0][r], s[1][r]), fmaxf(s[2][r], s[3][r]));
#pragma unroll
      for (int mk = 1; mk < 16; mk <<= 1) rm = fmaxf(rm, __shfl_xor(rm, mk));
      const float mn = fmaxf(mrow[r], rm);
      corr[r] = __expf(mrow[r] - mn);
      mrow[r] = mn;
      float ps = 0.f;
#pragma unroll
      for (int t = 0; t < 4; t++) {
        const float p = __expf(s[t][r] - mn);
        s[t][r] = p; ps += p;
      }
#pragma unroll
      for (int mk = 1; mk < 16; mk <<= 1) ps += __shfl_xor(ps, mk);
      lrow[r] = lrow[r] * corr[r] + ps;
    }
    // P -> LDS (bf16), same-wave roundtrip re-layouts C-frag -> A-frag
    ushort* pw = &Ps[wid][0];
#pragma unroll
    for (int r = 0; r < 4; r++) {
      const int row = lq * 4 + r;
#pragma unroll
      for (int t = 0; t < 4; t++) pw[row * 72 + t * 16 + lr] = f2b(s[t][r]);
    }
    // rescale O
#pragma unroll
    for (int dt = 0; dt < 8; dt++)
#pragma unroll
      for (int r = 0; r < 4; r++) o[dt][r] *= corr[r];
    // PV
#pragma unroll
    for (int kq = 0; kq < 2; kq++) {
      bf16x8 pa = *(const bf16x8*)(&pw[lr * 72 + kq * 32 + lq * 8]);
#pragma unroll
      for (int dt = 0; dt < 8; dt++) {
        bf16x8 vb = *(const bf16x8*)(&Vs[(dt * 16 + lr) * 72 + kq * 32 + lq * 8]);
        o[dt] = __builtin_amdgcn_mfma_f32_16x16x32_bf16(pa, vb, o[dt], 0, 0, 0);
      }
    }
  }
  // epilogue: normalize + store bf16 [L][H*D]
#pragma unroll
  for (int r = 0; r < 4; r++) {
    const float inv = 1.0f / lrow[r];
    const int row = q0 + lq * 4 + r;
#pragma unroll
    for (int dt = 0; dt < 8; dt++)
      Ob[(size_t)row * DIM + h * HD + dt * 16 + lr] = f2b(o[dt][r] * inv);
  }
}

extern "C" void kernel_launch(void* const* d_in, const int* in_sizes, int n_in,
                              void* d_out, int out_size, void* d_ws, size_t ws_size,
                              hipStream_t stream) {
  const float* x   = (const float*)d_in[0];
  const float* ctx = (const float*)d_in[1];
  const float* Wq  = (const float*)d_in[2];
  const float* bq  = (const float*)d_in[3];
  const float* Wk  = (const float*)d_in[4];
  const float* bk  = (const float*)d_in[5];
  const float* Wv  = (const float*)d_in[6];
  const float* bv  = (const float*)d_in[7];
  const float* Wo  = (const float*)d_in[8];
  const float* bo  = (const float*)d_in[9];
  const float* gq  = (const float*)d_in[10];
  const float* gk  = (const float*)d_in[11];

  char* ws = (char*)d_ws;
  ushort* wqt   = (ushort*)(ws);                 // [2048][2048] bf16   8.39MB
  ushort* wkt   = (ushort*)(ws + 8388608);       // [2048][4096] bf16  16.78MB
  ushort* wvt   = (ushort*)(ws + 25165824);      // [2048][4096] bf16  16.78MB
  ushort* wot   = (ushort*)(ws + 41943040);      // [2048][2048] bf16   8.39MB
  ushort* qb    = (ushort*)(ws + 50331648);      // [8192][2048] bf16  33.55MB
  ushort* kb    = (ushort*)(ws + 83886080);      // [512][2048]  bf16   2.10MB
  ushort* vt    = (ushort*)(ws + 85983232);      // [2048][512]  bf16   2.10MB (V^T per-head)
  float*  scr   = (float*)(ws + 88080384);       // fp32 scratch 67.1MB (q_raw / k_raw)
  ushort* attnb = (ushort*)(ws + 88080384);      // reuses scratch after rmsnorms

  // weight transposes (fp32 [K][N] -> bf16 [N][K])
  k_tcast<<<dim3(DIM / 32, DIM / 32), dim3(32, 8), 0, stream>>>(Wq, wqt, DIM, DIM);
  k_tcast<<<dim3(DIM / 32, CTX / 32), dim3(32, 8), 0, stream>>>(Wk, wkt, CTX, DIM);
  k_tcast<<<dim3(DIM / 32, CTX / 32), dim3(32, 8), 0, stream>>>(Wv, wvt, CTX, DIM);
  k_tcast<<<dim3(DIM / 32, DIM / 32), dim3(32, 8), 0, stream>>>(Wo, wot, DIM, DIM);

  // Q = rmsnorm(x@Wq + bq)*g_q, softmax scale folded in
  k_gemm_bt<0, 1><<<dim3(DIM / 128, L_SEQ / 128), 256, 0, stream>>>(x, wqt, bq, scr, L_SEQ, DIM, DIM);
  k_rmsnorm<<<L_SEQ, 256, 0, stream>>>(scr, qb, gq, 0.08838834764831843f);
  // K = rmsnorm(ctx@Wk + bk)*g_k
  k_gemm_bt<0, 1><<<dim3(DIM / 128, S_SEQ / 128), 256, 0, stream>>>(ctx, wkt, bk, scr, S_SEQ, DIM, CTX);
  k_rmsnorm<<<S_SEQ, 256, 0, stream>>>(scr, kb, gk, 1.0f);
  // V^T = (ctx@Wv + bv)^T  (bf16, per-head-friendly [n][s] layout)
  k_gemm_bt<2, 1><<<dim3(DIM / 128, S_SEQ / 128), 256, 0, stream>>>(ctx, wvt, bv, vt, S_SEQ, DIM, CTX);
  // attention
  k_attn<<<dim3(L_SEQ / 64, NH), 256, 0, stream>>>(qb, kb, vt, attnb);
  // out = attn @ Wo + bo  (fp32 out)
  k_gemm_bt<0, 0><<<dim3(DIM / 128, L_SEQ / 128), 256, 0, stream>>>(attnb, wot, bo, d_out, L_SEQ, DIM, DIM);
}